// Round 14
// baseline (109.700 us; speedup 1.0000x reference)
//
#include <hip/hip_runtime.h>

#define N_Q 4096
#define M_T 16384
#define D_ 32
#define OUT_ 16
#define EPS_ 1e-6f
#define NCHUNK 32            // M-chunks (blockIdx.x)
#define CPTS (M_T / NCHUNK)  // 512 points per chunk
#define TPTS 256             // points per LDS tile
#define NTILE (CPTS / TPTS)  // 2
#define NKEY 5               // per-lane keys (zero-loss for chunk top-5)
#define NCAND 12             // merged+rescored in phase 2
#define BIAS_ 128.0f
#define KMASK 0xFFFFC000u

typedef short bf16x8 __attribute__((ext_vector_type(8)));
typedef float f32x4 __attribute__((ext_vector_type(4)));

static __device__ __forceinline__ unsigned short f2bf(float f) {
  unsigned int u = __float_as_uint(f);
  return (unsigned short)((u + 0x7FFFu + ((u >> 16) & 1u)) >> 16);  // RNE
}
static __device__ __forceinline__ float bf2f(unsigned short h) {
  return __uint_as_float(((unsigned int)h) << 16);
}

__device__ __forceinline__ void chain5(unsigned int (&a)[NKEY], unsigned int v) {
#pragma unroll
  for (int i = 0; i < NKEY; ++i) {
    unsigned int lo = min(a[i], v);
    v = max(a[i], v);
    a[i] = lo;
  }
}
__device__ __forceinline__ void chain12(unsigned int (&a)[NCAND], unsigned int v) {
#pragma unroll
  for (int i = 0; i < NCAND; ++i) {
    unsigned int lo = min(a[i], v);
    v = max(a[i], v);
    a[i] = lo;
  }
}
__device__ __forceinline__ void insert5f(float (&s)[5], int (&id)[5], float v, int vi) {
  float cs = v; int ci = vi;
#pragma unroll
  for (int k = 0; k < 5; ++k) {
    bool lt = cs < s[k];
    float ts = s[k]; int ti = id[k];
    s[k] = lt ? cs : ts;  id[k] = lt ? ci : ti;
    cs   = lt ? ts : cs;  ci    = lt ? ti : ci;
  }
}

// ---------------------------------------------------------------------------
// Phase 0: scale by exp(w); fp32 copies + norms; bf16 hi/lo (queries) and
// bf16 hi (train) in tileT layout: row R, kgroup g at ushort offset
// (R>>4)*512 + g*128 + (R&15)*8.  Thread = (row, kgroup).
// ---------------------------------------------------------------------------
__global__ __launch_bounds__(256) void p0_prep(const float* __restrict__ x,
                                               const float* __restrict__ tx,
                                               const float* __restrict__ wts,
                                               float* __restrict__ xqs,
                                               float* __restrict__ xts,
                                               float* __restrict__ xqn,
                                               float* __restrict__ xtn,
                                               unsigned short* __restrict__ xq_h,
                                               unsigned short* __restrict__ xq_l,
                                               unsigned short* __restrict__ xt_h) {
  int gid = blockIdx.x * 256 + threadIdx.x;
  int row = gid >> 2;
  int g   = gid & 3;
  if (row >= N_Q + M_T) return;
  bool isq = row < N_Q;
  const float* src; float* dstf; unsigned short* dh; float* ndst; int ri;
  if (isq) { src = x;  dstf = xqs; dh = xq_h; ndst = xqn; ri = row; }
  else     { src = tx; dstf = xts; dh = xt_h; ndst = xtn; ri = row - N_Q; }
  float4 a = *(const float4*)(src + (size_t)ri * D_ + g * 8);
  float4 b = *(const float4*)(src + (size_t)ri * D_ + g * 8 + 4);
  float v[8] = {a.x, a.y, a.z, a.w, b.x, b.y, b.z, b.w};
  float nrm = 0.f;
  unsigned short hh[8], ll[8];
#pragma unroll
  for (int i = 0; i < 8; ++i) {
    float s = expf(wts[g * 8 + i]);
    v[i] /= s;
    nrm = fmaf(v[i], v[i], nrm);
    hh[i] = f2bf(v[i]);
    ll[i] = f2bf(v[i] - bf2f(hh[i]));
  }
  *(float4*)(dstf + (size_t)ri * D_ + g * 8)     = make_float4(v[0], v[1], v[2], v[3]);
  *(float4*)(dstf + (size_t)ri * D_ + g * 8 + 4) = make_float4(v[4], v[5], v[6], v[7]);
  nrm += __shfl_xor(nrm, 1);
  nrm += __shfl_xor(nrm, 2);
  if (g == 0) ndst[ri] = nrm;
  size_t ti = (size_t)(ri >> 4) * 512 + g * 128 + (ri & 15) * 8;  // ushort units
  uint4 hv;
  hv.x = hh[0] | (hh[1] << 16); hv.y = hh[2] | (hh[3] << 16);
  hv.z = hh[4] | (hh[5] << 16); hv.w = hh[6] | (hh[7] << 16);
  *(uint4*)(dh + ti) = hv;
  if (isq) {
    uint4 lv;
    lv.x = ll[0] | (ll[1] << 16); lv.y = ll[2] | (ll[3] << 16);
    lv.z = ll[4] | (ll[5] << 16); lv.w = ll[6] | (ll[7] << 16);
    *(uint4*)(xq_l + ti) = lv;
  }
}

// ---------------------------------------------------------------------------
// Phase 1: MFMA distance + branchless packed-key top-5.
// Block = 4 waves x 16 queries = 64 queries, one M-chunk of 512 points.
// dot ~= (a_hi + a_lo) . b_hi; error absorbed by exact top-12 rescore (p2).
// Merge: ONE shfl_xor(8) butterfly step (both sides hold merged list; ~30
// live regs, no spill) halves kbuf -> merge union member 15KB < loop 17KB
// -> LDS_Block 17.4KB -> 8 blocks/CU = 32 waves (r13: 25.6KB capped at 6
// blocks, 26% occupancy).
// C layout (r9..r13-verified): point col = lane&15, query row = (lane>>4)*4+reg.
// ---------------------------------------------------------------------------
union P1Smem {
  struct { unsigned short sh[TPTS * D_]; float stn[TPTS]; } loop;   // 16KB + 1KB
  struct { unsigned int kbuf[64 * 8 * NKEY]; unsigned int s1[64 * 4 * NKEY]; } mrg; // 10KB + 5KB
};

__global__ __launch_bounds__(256, 1) void p1_topk(const unsigned short* __restrict__ xq_h,
                                                  const unsigned short* __restrict__ xq_l,
                                                  const unsigned short* __restrict__ xt_h,
                                                  const float* __restrict__ xtn,
                                                  unsigned int* __restrict__ pkey) {
  __shared__ __align__(16) P1Smem sm;
  const int t = threadIdx.x;
  const int w = t >> 6, lane = t & 63;
  const int p = lane & 15, g = lane >> 4;
  const int chunk = blockIdx.x;
  const int qbB = blockIdx.y * 64;        // block query base
  const int qb  = qbB + w * 16;           // wave query base

  // A-fragments: loop-invariant, 8 VGPRs
  const size_t abase = (size_t)(qb >> 4) * 512 + g * 128 + p * 8;
  const bf16x8 ah = *(const bf16x8*)(xq_h + abase);
  const bf16x8 al = *(const bf16x8*)(xq_l + abase);
  const f32x4 zero = {0.f, 0.f, 0.f, 0.f};

  unsigned int key[4][NKEY];
#pragma unroll
  for (int r = 0; r < 4; ++r)
#pragma unroll
    for (int k = 0; k < NKEY; ++k) key[r][k] = 0xFFFFFFFFu;

  for (int tt = 0; tt < NTILE; ++tt) {
    const int pbase = chunk * CPTS + tt * TPTS;
    const size_t gb = (size_t)(pbase >> 4) * 512;
    __syncthreads();   // previous tile fully consumed
#pragma unroll
    for (int c = 0; c < 4; ++c) {
      __builtin_amdgcn_global_load_lds(
          (const __attribute__((address_space(1))) void*)(xt_h + gb + (size_t)(w * 4 + c) * 512 + (size_t)lane * 8),
          (__attribute__((address_space(3))) void*)(sm.loop.sh + (w * 4 + c) * 512),
          16, 0, 0);
    }
    sm.loop.stn[t] = xtn[pbase + t] + BIAS_;
    __syncthreads();   // drains vmcnt + lgkm: tile ready

#pragma unroll 2
    for (int s = 0; s < 16; ++s) {
      const bf16x8 bh = *(const bf16x8*)(sm.loop.sh + s * 512 + lane * 8);
      const float tnB = sm.loop.stn[s * 16 + p];
      f32x4 acc = __builtin_amdgcn_mfma_f32_16x16x32_bf16(al, bh, zero, 0, 0, 0);
      acc = __builtin_amdgcn_mfma_f32_16x16x32_bf16(ah, bh, acc, 0, 0, 0);
      const unsigned int kor = (unsigned int)(pbase + s * 16 + p);
#pragma unroll
      for (int r = 0; r < 4; ++r) {
        float v = fmaf(-2.0f, acc[r], tnB);            // > 0 by bias
        chain5(key[r], (__float_as_uint(v) & KMASK) | kor);
      }
    }
  }

  // ---- one butterfly step (xor 8): lanes p and p^8 end with identical
  //      merged lists; halves the LDS merge buffer ----
#pragma unroll
  for (int r = 0; r < 4; ++r) {
    unsigned int ov[NKEY];
#pragma unroll
    for (int k = 0; k < NKEY; ++k)
      ov[k] = (unsigned int)__shfl_xor((int)key[r][k], 8);
#pragma unroll
    for (int k = 0; k < NKEY; ++k) chain5(key[r], ov[k]);
  }

  // ---- two-stage LDS merge over the remaining 8 contributors/query ----
  __syncthreads();   // all waves done reading the tile buffer
  if (p < 8) {
#pragma unroll
    for (int r = 0; r < 4; ++r) {
      const int ql = w * 16 + g * 4 + r;   // local query id 0..63
#pragma unroll
      for (int k = 0; k < NKEY; ++k)
        sm.mrg.kbuf[(ql * 8 + p) * NKEY + k] = key[r][k];
    }
  }
  __syncthreads();

  {  // stage 1: 256 threads, each merges 2 contributors (10 contiguous dwords)
    const int ql = t & 63, h = t >> 6;     // h = 0..3
    unsigned int m1[NKEY];
#pragma unroll
    for (int k = 0; k < NKEY; ++k) m1[k] = 0xFFFFFFFFu;
    const unsigned int* src = sm.mrg.kbuf + (ql * 8 + h * 2) * NKEY;
#pragma unroll
    for (int i = 0; i < 2 * NKEY; ++i) chain5(m1, src[i]);
    __syncthreads();   // ordering: kbuf reads complete before s1 writes land
#pragma unroll
    for (int k = 0; k < NKEY; ++k)
      sm.mrg.s1[(ql * 4 + h) * NKEY + k] = m1[k];
  }
  __syncthreads();

  if (t < 64) {  // stage 2: one thread per query -> final 5 keys, coalesced out
    unsigned int m2[NKEY];
#pragma unroll
    for (int k = 0; k < NKEY; ++k) m2[k] = 0xFFFFFFFFu;
    const unsigned int* src = sm.mrg.s1 + t * 4 * NKEY;
#pragma unroll
    for (int i = 0; i < 4 * NKEY; ++i) chain5(m2, src[i]);
#pragma unroll
    for (int k = 0; k < NKEY; ++k)
      pkey[((size_t)chunk * N_Q + (qbB + t)) * NKEY + k] = m2[k];
  }
}

// ---------------------------------------------------------------------------
// Phase 2: one wave per query. 160 keys (32 chunks x 5) -> branchless top-12
// via chain + shfl_xor butterfly, exact fp32 rescore of 12, exact top-5.
// ---------------------------------------------------------------------------
__global__ __launch_bounds__(256) void p2_merge(const unsigned int* __restrict__ pkey,
                                                const float* __restrict__ xqs,
                                                const float* __restrict__ xqn,
                                                const float* __restrict__ xts,
                                                const float* __restrict__ xtn,
                                                const float* __restrict__ ty,
                                                float* __restrict__ out) {
  const int q    = (blockIdx.x * blockDim.x + threadIdx.x) >> 6;
  const int lane = threadIdx.x & 63;
  if (q >= N_Q) return;

  unsigned int s[NCAND];
#pragma unroll
  for (int m = 0; m < NCAND; ++m) s[m] = 0xFFFFFFFFu;
  {
    int c = lane;                      // keys 0..63
    int ch = c / 5, k = c - ch * 5;
    chain12(s, pkey[((size_t)ch * N_Q + q) * 5 + k]);
  }
  {
    int c = lane + 64;                 // keys 64..127
    int ch = c / 5, k = c - ch * 5;
    chain12(s, pkey[((size_t)ch * N_Q + q) * 5 + k]);
  }
  {
    unsigned int v = 0xFFFFFFFFu;      // keys 128..159
    if (lane < 32) {
      int c = 128 + lane;
      int ch = c / 5, k = c - ch * 5;
      v = pkey[((size_t)ch * N_Q + q) * 5 + k];
    }
    chain12(s, v);
  }

#pragma unroll
  for (int step = 1; step < 64; step <<= 1) {
    unsigned int ov[NCAND];
#pragma unroll
    for (int m = 0; m < NCAND; ++m) ov[m] = (unsigned int)__shfl_xor((int)s[m], step);
#pragma unroll
    for (int m = 0; m < NCAND; ++m) chain12(s, ov[m]);
  }

  unsigned int mykey = s[0];
#pragma unroll
  for (int m = 1; m < NCAND; ++m) mykey = (lane == m) ? s[m] : mykey;

  int   cidx = (int)(mykey & 0x3FFFu);
  float sqex = 3.0e38f;
  if (lane < NCAND) {
    float d = 0.f;
    const float* xr = xqs + (size_t)q * D_;
    const float* tr = xts + (size_t)cidx * D_;
#pragma unroll
    for (int c = 0; c < 8; ++c) {
      float4 a = *(const float4*)(xr + c * 4);
      float4 b = *(const float4*)(tr + c * 4);
      d = fmaf(a.x, b.x, d); d = fmaf(a.y, b.y, d);
      d = fmaf(a.z, b.z, d); d = fmaf(a.w, b.w, d);
    }
    sqex = fmaxf(xqn[q] + xtn[cidx] - 2.0f * d, 0.0f);
  }

  float s5[5]; int id5[5];
#pragma unroll
  for (int k = 0; k < 5; ++k) { s5[k] = 3.0e38f; id5[k] = 0; }
#pragma unroll
  for (int m = 0; m < NCAND; ++m) {
    float v  = __shfl(sqex, m);
    int   vi = __shfl(cidx, m);
    if (v < s5[4]) insert5f(s5, id5, v, vi);   // wave-uniform branch
  }

  float dinv[5]; float wsum = 0.f;
#pragma unroll
  for (int k = 0; k < 5; ++k) {
    dinv[k] = 1.0f / sqrtf(s5[k] + EPS_);
    wsum += dinv[k];
  }
  if (lane < OUT_) {
    float acc = 0.f;
#pragma unroll
    for (int k = 0; k < 5; ++k)
      acc = fmaf(dinv[k] / wsum, ty[(size_t)id5[k] * OUT_ + lane], acc);
    out[(size_t)q * OUT_ + lane] = acc;
  }
}

// ---------------------------------------------------------------------------
extern "C" void kernel_launch(void* const* d_in, const int* in_sizes, int n_in,
                              void* d_out, int out_size, void* d_ws, size_t ws_size,
                              hipStream_t stream) {
  const float* x   = (const float*)d_in[0];
  const float* tx  = (const float*)d_in[1];
  const float* ty  = (const float*)d_in[2];
  const float* wts = (const float*)d_in[3];
  float* out = (float*)d_out;

  char* ws = (char*)d_ws;
  size_t off = 0;
  float* xqs = (float*)(ws + off); off += (size_t)N_Q * D_ * 4;      // 512KB
  float* xts = (float*)(ws + off); off += (size_t)M_T * D_ * 4;      // 2MB
  float* xqn = (float*)(ws + off); off += (size_t)N_Q * 4;
  float* xtn = (float*)(ws + off); off += (size_t)M_T * 4;
  unsigned short* xq_h = (unsigned short*)(ws + off); off += (size_t)N_Q * D_ * 2;
  unsigned short* xq_l = (unsigned short*)(ws + off); off += (size_t)N_Q * D_ * 2;
  unsigned short* xt_h = (unsigned short*)(ws + off); off += (size_t)M_T * D_ * 2;
  unsigned int* pkey = (unsigned int*)(ws + off);                    // 2.6MB

  p0_prep<<<dim3((N_Q + M_T) * 4 / 256), dim3(256), 0, stream>>>(
      x, tx, wts, xqs, xts, xqn, xtn, xq_h, xq_l, xt_h);
  p1_topk<<<dim3(NCHUNK, N_Q / 64), dim3(256), 0, stream>>>(
      xq_h, xq_l, xt_h, xtn, pkey);
  p2_merge<<<dim3(N_Q * 64 / 256), dim3(256), 0, stream>>>(
      pkey, xqs, xqn, xts, xtn, ty, out);
}